// Round 1
// baseline (435.157 us; speedup 1.0000x reference)
//
#include <hip/hip_runtime.h>
#include <hip/hip_bf16.h>

// QuantizedLinearINT4: out = x @ dequant(W).T + bias
// x: [4,2048,4096] f32 -> M=8192, K=4096 ; W: int4 packed (2 nibbles / int32 low byte), OUT=4096
// Strategy: dequant W -> bf16 [N][K] (ws), cast x -> bf16 [M][K] (ws), then
// m97-structure 128x128 bf16 MFMA GEMM-BT with global_load_lds(16B) staging,
// fused bias epilogue, XCD-bijective block swizzle.

typedef __bf16 bf16;
typedef __attribute__((ext_vector_type(8))) __bf16 bf16x8;
typedef __attribute__((ext_vector_type(4))) float f32x4;
typedef __attribute__((ext_vector_type(4))) unsigned int u32x4;

#define OUT_DIM 4096
#define IN_DIM  4096
#define M_DIM   8192

#define BM 128
#define BN 128
#define BK 64

// ---------- Pass 1: dequant int4 -> bf16 W[OUT][IN] ----------
// weight_packed[k] is int32 in [0,256): low nibble = weight 2k, high nibble = weight 2k+1
// w[o][i] = (nib - zp[o]) * scale[o]
__global__ __launch_bounds__(256) void dequant_w_kernel(
    const int* __restrict__ wp, const float* __restrict__ scale,
    const float* __restrict__ zp, bf16* __restrict__ W)
{
  const int t = blockIdx.x * 256 + threadIdx.x;     // OUT*IN/8 = 2,097,152 threads
  const long j = (long)t * 8;                       // first weight index
  const int o = (int)(j >> 12);                     // j / 4096 (8 weights never cross a row)
  const float s = scale[o];
  const float zs = zp[o] * s;
  const int4 p = *(const int4*)(wp + (long)t * 4);
  const int v[4] = {p.x, p.y, p.z, p.w};
  union { bf16 h[8]; u32x4 u; } r;
#pragma unroll
  for (int q = 0; q < 4; ++q) {
    r.h[2*q]   = (bf16)((float)(v[q] & 15) * s - zs);
    r.h[2*q+1] = (bf16)((float)((v[q] >> 4) & 15) * s - zs);
  }
  *(u32x4*)(W + j) = r.u;
}

// ---------- Pass 2: cast x f32 -> bf16 ----------
__global__ __launch_bounds__(256) void cvt_x_kernel(
    const float* __restrict__ x, bf16* __restrict__ xb)
{
  const long t = (long)blockIdx.x * 256 + threadIdx.x;  // M*K/8 = 4,194,304 threads
  const long i = t * 8;
  const f32x4 a = *(const f32x4*)(x + i);
  const f32x4 b = *(const f32x4*)(x + i + 4);
  union { bf16 h[8]; u32x4 u; } r;
#pragma unroll
  for (int q = 0; q < 4; ++q) { r.h[q] = (bf16)a[q]; r.h[4+q] = (bf16)b[q]; }
  *(u32x4*)(xb + i) = r.u;
}

// ---------- Pass 3: C[M][N] = A[M][K] * B[N][K]^T + bias, bf16 MFMA ----------
// m97 structure: 128x128 tile, BK=64, 4 waves (2x2), each wave 64x64 out = 4x4
// fragments of 16x16, global_load_lds width=16 staging, single-buffered LDS.
__global__ __launch_bounds__(256) void gemm_bt_bias_kernel(
    const bf16* __restrict__ A, const bf16* __restrict__ B,
    const float* __restrict__ bias, float* __restrict__ C,
    const int M, const int N, const int K)
{
  __shared__ bf16 As[BM][BK];   // 16 KB
  __shared__ bf16 Bs[BN][BK];   // 16 KB

  // XCD-aware bijective swizzle (grid % 8 == 0: 2048 blocks)
  const int nwg = gridDim.x;
  const int cpx = nwg >> 3;
  const int bid = blockIdx.x;
  const int swz = (bid & 7) * cpx + (bid >> 3);
  const int nbn = N / BN;
  const int bm = swz / nbn;
  const int bn = swz % nbn;

  const int tid  = threadIdx.x;
  const int wave = tid >> 6;
  const int lane = tid & 63;
  const int wr = wave >> 1;      // wave row (0..1) -> 64-row strip
  const int wc = wave & 1;       // wave col (0..1) -> 64-col strip

  const long row0 = (long)bm * BM;
  const long col0 = (long)bn * BN;

  f32x4 acc[4][4] = {};

  for (int kt = 0; kt < K / BK; ++kt) {
    __syncthreads();  // previous compute done before overwriting LDS
    const long kbase = (long)kt * BK;
    // Stage A tile: 16 KB = 4 block-wide issues of 4 KB (256 lanes x 16 B)
#pragma unroll
    for (int r = 0; r < 4; ++r) {
      const int off  = r * 4096 + tid * 16;       // byte offset in As (row-major [128][64])
      const int arow = off >> 7;                  // / 128 bytes per row
      const int acol = (off & 127) >> 1;          // bf16 col within row
      const bf16* src = A + (row0 + arow) * (long)K + kbase + acol;
      __builtin_amdgcn_global_load_lds(
          (const __attribute__((address_space(1))) void*)src,
          (__attribute__((address_space(3))) void*)((char*)&As[0][0] + off),
          16, 0, 0);
    }
    // Stage B tile
#pragma unroll
    for (int r = 0; r < 4; ++r) {
      const int off  = r * 4096 + tid * 16;
      const int brow = off >> 7;
      const int bcol = (off & 127) >> 1;
      const bf16* src = B + (col0 + brow) * (long)K + kbase + bcol;
      __builtin_amdgcn_global_load_lds(
          (const __attribute__((address_space(1))) void*)src,
          (__attribute__((address_space(3))) void*)((char*)&Bs[0][0] + off),
          16, 0, 0);
    }
    asm volatile("s_waitcnt vmcnt(0)" ::: "memory");
    __syncthreads();

#pragma unroll
    for (int ks = 0; ks < 2; ++ks) {
      bf16x8 af[4], bf_[4];
      const int ak = ks * 32 + (lane >> 4) * 8;   // 8 contiguous K elems per lane
#pragma unroll
      for (int i = 0; i < 4; ++i) {
        const int ar = wr * 64 + i * 16 + (lane & 15);
        af[i]  = *(const bf16x8*)&As[ar][ak];
        const int br = wc * 64 + i * 16 + (lane & 15);
        bf_[i] = *(const bf16x8*)&Bs[br][ak];
      }
#pragma unroll
      for (int i = 0; i < 4; ++i)
#pragma unroll
        for (int j = 0; j < 4; ++j)
          acc[i][j] = __builtin_amdgcn_mfma_f32_16x16x32_bf16(af[i], bf_[j], acc[i][j], 0, 0, 0);
    }
  }

  // Epilogue: C/D layout col=lane&15, row=(lane>>4)*4+reg
  const int cr = lane >> 4;
  const int cc = lane & 15;
#pragma unroll
  for (int j = 0; j < 4; ++j) {
    const long gc = col0 + wc * 64 + j * 16 + cc;
    const float bv = bias[gc];
#pragma unroll
    for (int i = 0; i < 4; ++i) {
      const long gr = row0 + wr * 64 + i * 16 + cr * 4;
      float* cp = C + gr * (long)N + gc;
#pragma unroll
      for (int r = 0; r < 4; ++r)
        cp[(long)r * N] = acc[i][j][r] + bv;
    }
  }
}

extern "C" void kernel_launch(void* const* d_in, const int* in_sizes, int n_in,
                              void* d_out, int out_size, void* d_ws, size_t ws_size,
                              hipStream_t stream)
{
  const float* x     = (const float*)d_in[0];   // [8192, 4096] f32
  const int*   wp    = (const int*)d_in[1];     // [8388608] int32 (2 nibbles each)
  const float* scale = (const float*)d_in[2];   // [4096]
  const float* zp    = (const float*)d_in[3];   // [4096]
  const float* bias  = (const float*)d_in[4];   // [4096]
  float* out = (float*)d_out;                   // [8192, 4096] f32

  bf16* Wb = (bf16*)d_ws;                                            // 33,554,432 B
  bf16* Xb = (bf16*)((char*)d_ws + (size_t)OUT_DIM * IN_DIM * 2);    // 67,108,864 B

  // Pass 1: dequant W (2,097,152 threads)
  dequant_w_kernel<<<(OUT_DIM * (long)IN_DIM / 8) / 256, 256, 0, stream>>>(wp, scale, zp, Wb);
  // Pass 2: cast x (4,194,304 threads)
  cvt_x_kernel<<<(M_DIM * (long)IN_DIM / 8) / 256, 256, 0, stream>>>(x, Xb);
  // Pass 3: GEMM, grid = (8192/128)*(4096/128) = 64*32 = 2048 blocks
  gemm_bt_bias_kernel<<<(M_DIM / BM) * (OUT_DIM / BN), 256, 0, stream>>>(
      Xb, Wb, bias, out, M_DIM, OUT_DIM, IN_DIM);
}

// Round 3
// 300.211 us; speedup vs baseline: 1.4495x; 1.4495x over previous
//
#include <hip/hip_runtime.h>
#include <hip/hip_bf16.h>

// QuantizedLinearINT4: out = x @ dequant(W).T + bias
// M=8192, N=OUT=4096, K=IN=4096.
// Pass 1: dequant int4 -> bf16 W[N][K]; Pass 2: cast x f32 -> bf16 X[M][K];
// Pass 3: 256x256 8-phase bf16 MFMA GEMM (T1 XCD swizzle + T2 st_16x32 LDS
// swizzle + T3/T4 counted-vmcnt phase pipeline + T5 setprio), fused bias.
// Round-2 fix: K-half staging offset was 16 ELEMENTS (should be 32) — the
// Ak1/Bk1 halves held k[16,48) instead of k[32,64).

typedef __bf16 bf16;
typedef __attribute__((ext_vector_type(8))) __bf16 bf16x8;
typedef __attribute__((ext_vector_type(4))) float f32x4;
typedef __attribute__((ext_vector_type(4))) unsigned int u32x4;

#define OUT_DIM 4096
#define IN_DIM  4096
#define M_DIM   8192

// ---------- Pass 1: dequant int4 -> bf16 W[OUT][IN] ----------
__global__ __launch_bounds__(256) void dequant_w_kernel(
    const int* __restrict__ wp, const float* __restrict__ scale,
    const float* __restrict__ zp, bf16* __restrict__ W)
{
  const int t = blockIdx.x * 256 + threadIdx.x;
  const long j = (long)t * 8;
  const int o = (int)(j >> 12);
  const float s = scale[o];
  const float zs = zp[o] * s;
  const int4 p = *(const int4*)(wp + (long)t * 4);
  const int v[4] = {p.x, p.y, p.z, p.w};
  union { bf16 h[8]; u32x4 u; } r;
#pragma unroll
  for (int q = 0; q < 4; ++q) {
    r.h[2*q]   = (bf16)((float)(v[q] & 15) * s - zs);
    r.h[2*q+1] = (bf16)((float)((v[q] >> 4) & 15) * s - zs);
  }
  *(u32x4*)(W + j) = r.u;
}

// ---------- Pass 2: cast x f32 -> bf16 ----------
__global__ __launch_bounds__(256) void cvt_x_kernel(
    const float* __restrict__ x, bf16* __restrict__ xb)
{
  const long t = (long)blockIdx.x * 256 + threadIdx.x;
  const long i = t * 8;
  const f32x4 a = *(const f32x4*)(x + i);
  const f32x4 b = *(const f32x4*)(x + i + 4);
  union { bf16 h[8]; u32x4 u; } r;
#pragma unroll
  for (int q = 0; q < 4; ++q) { r.h[q] = (bf16)a[q]; r.h[4+q] = (bf16)b[q]; }
  *(u32x4*)(xb + i) = r.u;
}

// ---------- Pass 3: 256x256 8-phase GEMM-BT with fused bias ----------
// C[M][N] = A[M][K] * B[N][K]^T + bias.  512 threads = 8 waves (2M x 4N).
// LDS halves (16KB each): [buf][0]=A k0-31, [1]=A k32-63, [2]=B k0-31, [3]=B k32-63,
// each [256 rows][32 k] bf16 with st_16x32 swizzle (byte ^= ((byte>>9)&1)<<5).
// Stage stream: per tile T, halves staged in order {Ak0,Bk0,Ak1,Bk1}, one per
// phase, 4 phases ahead of consumption; vmcnt(4) at even phases (never 0 in
// steady state). Tile T computed in 4 phases: (ks,mh) = (0,0),(0,1),(1,0),(1,1).
__global__ __launch_bounds__(512, 2) void gemm_bt_bias_kernel(
    const bf16* __restrict__ A, const bf16* __restrict__ B,
    const float* __restrict__ bias, float* __restrict__ C)
{
  const int M = M_DIM, N = OUT_DIM, K = IN_DIM;
  const int NT = IN_DIM / 64;            // 64 K-tiles

  __shared__ bf16 sm[2][4][256][32];     // 128 KiB

  // T1: XCD-aware bijective swizzle (512 blocks, 512 % 8 == 0)
  const int bid = blockIdx.x;
  const int swz = (bid & 7) * (512 / 8) + (bid >> 3);
  const int bm = swz >> 4;               // 32 row-tiles
  const int bn = swz & 15;               // 16 col-tiles

  const int tid  = threadIdx.x;
  const int wave = tid >> 6;
  const int lane = tid & 63;
  const int wr = wave >> 2;              // 0..1 -> 128-row strip
  const int wc = wave & 3;               // 0..3 -> 64-col strip

  const long row0 = (long)bm * 256;
  const long col0 = (long)bn * 256;

  // --- staging source addresses (pre-swizzled: linear LDS dest, swizzled global src) ---
  const int L0 = tid * 16;
  const int L1 = 8192 + tid * 16;
  const int Lw0 = L0 ^ (((L0 >> 9) & 1) << 5);
  const int Lw1 = L1 ^ (((L1 >> 9) & 1) << 5);
  const int sr0 = Lw0 >> 6, sc0 = (Lw0 & 63) >> 1;   // row, bf16-col within [256][32] half
  const int sr1 = Lw1 >> 6, sc1 = (Lw1 & 63) >> 1;
  const bf16* a0 = A + (row0 + sr0) * (long)K + sc0;
  const bf16* a1 = A + (row0 + sr1) * (long)K + sc1;
  const bf16* b0 = B + (col0 + sr0) * (long)K + sc0;
  const bf16* b1 = B + (col0 + sr1) * (long)K + sc1;

#define STAGE(P0, P1, HALF, KOFF) do {                                          \
    __builtin_amdgcn_global_load_lds(                                           \
        (const __attribute__((address_space(1))) void*)((P0) + (KOFF)),         \
        (__attribute__((address_space(3))) void*)((char*)(HALF) + L0), 16, 0, 0);\
    __builtin_amdgcn_global_load_lds(                                           \
        (const __attribute__((address_space(1))) void*)((P1) + (KOFF)),         \
        (__attribute__((address_space(3))) void*)((char*)(HALF) + L1), 16, 0, 0);\
  } while (0)

  // --- ds_read per-lane constants (swizzle folds to ^((lane&8)<<2)) ---
  const int lane15 = lane & 15;
  const int rb = (lane15 * 64 + ((lane >> 4) << 4)) ^ ((lane & 8) << 2);
  const int wrB = wr * 8192;             // byte offset of wave's 128-row strip in A half
  const int wcB = wc * 4096;             // byte offset of wave's 64-row strip in B half

  f32x4 acc[8][4] = {};

#define PHASE(BUF, KS, MH, STAGE_STMT, VM_STMT) do {                            \
    VM_STMT;                                                                    \
    __builtin_amdgcn_s_barrier();                                               \
    const char* Ab = (const char*)&sm[BUF][KS][0][0];                           \
    const char* Bb = (const char*)&sm[BUF][2 + KS][0][0];                       \
    bf16x8 af0 = *(const bf16x8*)(Ab + wrB + (MH)*4096 + 0*1024 + rb);          \
    bf16x8 af1 = *(const bf16x8*)(Ab + wrB + (MH)*4096 + 1*1024 + rb);          \
    bf16x8 af2 = *(const bf16x8*)(Ab + wrB + (MH)*4096 + 2*1024 + rb);          \
    bf16x8 af3 = *(const bf16x8*)(Ab + wrB + (MH)*4096 + 3*1024 + rb);          \
    bf16x8 bf0 = *(const bf16x8*)(Bb + wcB + 0*1024 + rb);                      \
    bf16x8 bf1 = *(const bf16x8*)(Bb + wcB + 1*1024 + rb);                      \
    bf16x8 bf2 = *(const bf16x8*)(Bb + wcB + 2*1024 + rb);                      \
    bf16x8 bf3 = *(const bf16x8*)(Bb + wcB + 3*1024 + rb);                      \
    STAGE_STMT;                                                                 \
    __builtin_amdgcn_s_barrier();                                               \
    asm volatile("s_waitcnt lgkmcnt(0)" ::: "memory");                          \
    __builtin_amdgcn_s_setprio(1);                                              \
    acc[(MH)*4+0][0] = __builtin_amdgcn_mfma_f32_16x16x32_bf16(af0, bf0, acc[(MH)*4+0][0], 0, 0, 0); \
    acc[(MH)*4+0][1] = __builtin_amdgcn_mfma_f32_16x16x32_bf16(af0, bf1, acc[(MH)*4+0][1], 0, 0, 0); \
    acc[(MH)*4+0][2] = __builtin_amdgcn_mfma_f32_16x16x32_bf16(af0, bf2, acc[(MH)*4+0][2], 0, 0, 0); \
    acc[(MH)*4+0][3] = __builtin_amdgcn_mfma_f32_16x16x32_bf16(af0, bf3, acc[(MH)*4+0][3], 0, 0, 0); \
    acc[(MH)*4+1][0] = __builtin_amdgcn_mfma_f32_16x16x32_bf16(af1, bf0, acc[(MH)*4+1][0], 0, 0, 0); \
    acc[(MH)*4+1][1] = __builtin_amdgcn_mfma_f32_16x16x32_bf16(af1, bf1, acc[(MH)*4+1][1], 0, 0, 0); \
    acc[(MH)*4+1][2] = __builtin_amdgcn_mfma_f32_16x16x32_bf16(af1, bf2, acc[(MH)*4+1][2], 0, 0, 0); \
    acc[(MH)*4+1][3] = __builtin_amdgcn_mfma_f32_16x16x32_bf16(af1, bf3, acc[(MH)*4+1][3], 0, 0, 0); \
    acc[(MH)*4+2][0] = __builtin_amdgcn_mfma_f32_16x16x32_bf16(af2, bf0, acc[(MH)*4+2][0], 0, 0, 0); \
    acc[(MH)*4+2][1] = __builtin_amdgcn_mfma_f32_16x16x32_bf16(af2, bf1, acc[(MH)*4+2][1], 0, 0, 0); \
    acc[(MH)*4+2][2] = __builtin_amdgcn_mfma_f32_16x16x32_bf16(af2, bf2, acc[(MH)*4+2][2], 0, 0, 0); \
    acc[(MH)*4+2][3] = __builtin_amdgcn_mfma_f32_16x16x32_bf16(af2, bf3, acc[(MH)*4+2][3], 0, 0, 0); \
    acc[(MH)*4+3][0] = __builtin_amdgcn_mfma_f32_16x16x32_bf16(af3, bf0, acc[(MH)*4+3][0], 0, 0, 0); \
    acc[(MH)*4+3][1] = __builtin_amdgcn_mfma_f32_16x16x32_bf16(af3, bf1, acc[(MH)*4+3][1], 0, 0, 0); \
    acc[(MH)*4+3][2] = __builtin_amdgcn_mfma_f32_16x16x32_bf16(af3, bf2, acc[(MH)*4+3][2], 0, 0, 0); \
    acc[(MH)*4+3][3] = __builtin_amdgcn_mfma_f32_16x16x32_bf16(af3, bf3, acc[(MH)*4+3][3], 0, 0, 0); \
    __builtin_amdgcn_s_setprio(0);                                              \
  } while (0)

  // Prologue: stage tile 0's 4 halves into buf 0 (order Ak0, Bk0, Ak1, Bk1)
  STAGE(a0, a1, &sm[0][0][0][0], 0);
  STAGE(b0, b1, &sm[0][2][0][0], 0);
  STAGE(a0, a1, &sm[0][1][0][0], 32);
  STAGE(b0, b1, &sm[0][3][0][0], 32);

  for (int T = 0; T < NT; ++T) {
    const int buf = T & 1;
    const int nbuf = buf ^ 1;
    const int nko = (T + 1) * 64;        // next tile's K element offset
    const bool st = (T + 1 < NT);

    // phase 0: compute (ks=0, mh=0); stage next tile A k0-31
    PHASE(buf, 0, 0,
          { if (st) STAGE(a0, a1, &sm[nbuf][0][0][0], nko); },
          { asm volatile("s_waitcnt vmcnt(4)" ::: "memory"); });
    // phase 1: compute (ks=0, mh=1); stage next tile B k0-31
    PHASE(buf, 0, 1,
          { if (st) STAGE(b0, b1, &sm[nbuf][2][0][0], nko); },
          { });
    // phase 2: compute (ks=1, mh=0); stage next tile A k32-63
    PHASE(buf, 1, 0,
          { if (st) STAGE(a0, a1, &sm[nbuf][1][0][0], nko + 32); },
          { if (T == NT - 1) asm volatile("s_waitcnt vmcnt(0)" ::: "memory");
            else             asm volatile("s_waitcnt vmcnt(4)" ::: "memory"); });
    // phase 3: compute (ks=1, mh=1); stage next tile B k32-63
    PHASE(buf, 1, 1,
          { if (st) STAGE(b0, b1, &sm[nbuf][3][0][0], nko + 32); },
          { });
  }

  // Epilogue: C/D layout col=lane&15, row=(lane>>4)*4+reg; fused bias.
  const long cr0 = row0 + wr * 128 + ((lane >> 4) << 2);
  const long cc0 = col0 + wc * 64 + lane15;
#pragma unroll
  for (int j = 0; j < 4; ++j) {
    const long gc = cc0 + j * 16;
    const float bv = bias[gc];
#pragma unroll
    for (int mf = 0; mf < 8; ++mf) {
      float* cp = C + (cr0 + mf * 16) * (long)N + gc;
#pragma unroll
      for (int r = 0; r < 4; ++r)
        cp[(long)r * N] = acc[mf][j][r] + bv;
    }
  }
#undef PHASE
#undef STAGE
}

extern "C" void kernel_launch(void* const* d_in, const int* in_sizes, int n_in,
                              void* d_out, int out_size, void* d_ws, size_t ws_size,
                              hipStream_t stream)
{
  const float* x     = (const float*)d_in[0];
  const int*   wp    = (const int*)d_in[1];
  const float* scale = (const float*)d_in[2];
  const float* zp    = (const float*)d_in[3];
  const float* bias  = (const float*)d_in[4];
  float* out = (float*)d_out;

  bf16* Wb = (bf16*)d_ws;
  bf16* Xb = (bf16*)((char*)d_ws + (size_t)OUT_DIM * IN_DIM * 2);

  dequant_w_kernel<<<(OUT_DIM * (long)IN_DIM / 8) / 256, 256, 0, stream>>>(wp, scale, zp, Wb);
  cvt_x_kernel<<<(M_DIM * (long)IN_DIM / 8) / 256, 256, 0, stream>>>(x, Xb);
  // grid = (8192/256)*(4096/256) = 32*16 = 512 blocks, 512 threads
  gemm_bt_bias_kernel<<<512, 512, 0, stream>>>(Xb, Wb, bias, out);
}

// Round 4
// 281.862 us; speedup vs baseline: 1.5439x; 1.0651x over previous
//
#include <hip/hip_runtime.h>
#include <hip/hip_bf16.h>

// QuantizedLinearINT4: out = x @ dequant(W).T + bias
// M=8192, N=OUT=4096, K=IN=4096.
// Round-4: 2-phase-per-K-tile 256x256 GEMM. Removed forced lgkmcnt(0) drain
// (compiler emits counted lgkm waits -> ds_read/MFMA overlap) and merged mh
// sub-phases (12 ds_read + 32 MFMA per phase, no duplicate B reads).
// Counted vmcnt(4) staging cadence, st_16x32 LDS swizzle, XCD swizzle, setprio.

typedef __bf16 bf16;
typedef __attribute__((ext_vector_type(8))) __bf16 bf16x8;
typedef __attribute__((ext_vector_type(4))) float f32x4;
typedef __attribute__((ext_vector_type(4))) unsigned int u32x4;

#define OUT_DIM 4096
#define IN_DIM  4096
#define M_DIM   8192

// ---------- Pass 1: dequant int4 -> bf16 W[OUT][IN] ----------
__global__ __launch_bounds__(256) void dequant_w_kernel(
    const int* __restrict__ wp, const float* __restrict__ scale,
    const float* __restrict__ zp, bf16* __restrict__ W)
{
  const int t = blockIdx.x * 256 + threadIdx.x;
  const long j = (long)t * 8;
  const int o = (int)(j >> 12);
  const float s = scale[o];
  const float zs = zp[o] * s;
  const int4 p = *(const int4*)(wp + (long)t * 4);
  const int v[4] = {p.x, p.y, p.z, p.w};
  union { bf16 h[8]; u32x4 u; } r;
#pragma unroll
  for (int q = 0; q < 4; ++q) {
    r.h[2*q]   = (bf16)((float)(v[q] & 15) * s - zs);
    r.h[2*q+1] = (bf16)((float)((v[q] >> 4) & 15) * s - zs);
  }
  *(u32x4*)(W + j) = r.u;
}

// ---------- Pass 2: cast x f32 -> bf16 ----------
__global__ __launch_bounds__(256) void cvt_x_kernel(
    const float* __restrict__ x, bf16* __restrict__ xb)
{
  const long t = (long)blockIdx.x * 256 + threadIdx.x;
  const long i = t * 8;
  const f32x4 a = *(const f32x4*)(x + i);
  const f32x4 b = *(const f32x4*)(x + i + 4);
  union { bf16 h[8]; u32x4 u; } r;
#pragma unroll
  for (int q = 0; q < 4; ++q) { r.h[q] = (bf16)a[q]; r.h[4+q] = (bf16)b[q]; }
  *(u32x4*)(xb + i) = r.u;
}

// ---------- Pass 3: 256x256 2-phase-per-K-tile GEMM-BT with fused bias ----------
// C[M][N] = A[M][K] * B[N][K]^T + bias.  512 threads = 8 waves (2M x 4N).
// LDS halves (16KB each): [buf][0]=A k0-31, [1]=A k32-63, [2]=B k0-31, [3]=B k32-63,
// each [256 rows][32 k] bf16 with st_16x32 swizzle (byte ^= ((byte>>9)&1)<<5).
// Per phase: vmcnt(4) -> barrier -> 12 ds_read_b128 (4 B + 8 A) -> stage 2
// half-tiles (4 gload_lds) -> 32 MFMA (compiler-counted lgkm waits).
__global__ __launch_bounds__(512, 2) void gemm_bt_bias_kernel(
    const bf16* __restrict__ A, const bf16* __restrict__ B,
    const float* __restrict__ bias, float* __restrict__ C)
{
  const int N = OUT_DIM, K = IN_DIM;
  const int NT = IN_DIM / 64;            // 64 K-tiles

  __shared__ bf16 sm[2][4][256][32];     // 128 KiB

  // T1: XCD-aware bijective swizzle (512 blocks, 512 % 8 == 0)
  const int bid = blockIdx.x;
  const int swz = (bid & 7) * (512 / 8) + (bid >> 3);
  const int bm = swz >> 4;               // 32 row-tiles
  const int bn = swz & 15;               // 16 col-tiles

  const int tid  = threadIdx.x;
  const int wave = tid >> 6;
  const int lane = tid & 63;
  const int wr = wave >> 2;              // 0..1 -> 128-row strip
  const int wc = wave & 3;               // 0..3 -> 64-col strip

  const long row0 = (long)bm * 256;
  const long col0 = (long)bn * 256;

  // --- staging source addresses (pre-swizzled: linear LDS dest, swizzled global src) ---
  const int L0 = tid * 16;
  const int L1 = 8192 + tid * 16;
  const int Lw0 = L0 ^ (((L0 >> 9) & 1) << 5);
  const int Lw1 = L1 ^ (((L1 >> 9) & 1) << 5);
  const int sr0 = Lw0 >> 6, sc0 = (Lw0 & 63) >> 1;   // row, bf16-col within [256][32] half
  const int sr1 = Lw1 >> 6, sc1 = (Lw1 & 63) >> 1;
  const bf16* a0 = A + (row0 + sr0) * (long)K + sc0;
  const bf16* a1 = A + (row0 + sr1) * (long)K + sc1;
  const bf16* b0 = B + (col0 + sr0) * (long)K + sc0;
  const bf16* b1 = B + (col0 + sr1) * (long)K + sc1;

#define STAGE(P0, P1, HALF, KOFF) do {                                          \
    __builtin_amdgcn_global_load_lds(                                           \
        (const __attribute__((address_space(1))) void*)((P0) + (KOFF)),         \
        (__attribute__((address_space(3))) void*)((char*)(HALF) + L0), 16, 0, 0);\
    __builtin_amdgcn_global_load_lds(                                           \
        (const __attribute__((address_space(1))) void*)((P1) + (KOFF)),         \
        (__attribute__((address_space(3))) void*)((char*)(HALF) + L1), 16, 0, 0);\
  } while (0)

  // --- ds_read per-lane constants (swizzle folds to ^((lane&8)<<2)) ---
  const int lane15 = lane & 15;
  const int rb = (lane15 * 64 + ((lane >> 4) << 4)) ^ ((lane & 8) << 2);
  const int wrB = wr * 8192;             // byte offset of wave's 128-row strip in A half
  const int wcB = wc * 4096;             // byte offset of wave's 64-row strip in B half

  f32x4 acc[8][4] = {};

  // Phase: reads B frags first (reused by all 8 A frags), then A; stage-issue
  // before MFMAs; NO explicit lgkm drain -- compiler interleaves MFMA with
  // in-flight ds_reads via counted lgkmcnt.
#define PHASE(BUF, KS, STAGE_STMT, VM_STMT) do {                                \
    VM_STMT;                                                                    \
    __builtin_amdgcn_s_barrier();                                               \
    asm volatile("" ::: "memory");  /* keep reads below the barrier */          \
    const char* Ab = (const char*)&sm[BUF][KS][0][0];                           \
    const char* Bb = (const char*)&sm[BUF][2 + (KS)][0][0];                     \
    bf16x8 fb[4], fa[8];                                                        \
    _Pragma("unroll")                                                           \
    for (int f = 0; f < 4; ++f) fb[f] = *(const bf16x8*)(Bb + wcB + f*1024 + rb); \
    _Pragma("unroll")                                                           \
    for (int f = 0; f < 8; ++f) fa[f] = *(const bf16x8*)(Ab + wrB + f*1024 + rb); \
    STAGE_STMT;                                                                 \
    __builtin_amdgcn_s_setprio(1);                                              \
    _Pragma("unroll")                                                           \
    for (int i = 0; i < 8; ++i)                                                 \
      _Pragma("unroll")                                                         \
      for (int j = 0; j < 4; ++j)                                               \
        acc[i][j] = __builtin_amdgcn_mfma_f32_16x16x32_bf16(fa[i], fb[j], acc[i][j], 0, 0, 0); \
    __builtin_amdgcn_s_setprio(0);                                              \
  } while (0)

  // Prologue: stage tile 0's 4 halves into buf 0 (order Ak0, Bk0, Ak1, Bk1)
  STAGE(a0, a1, &sm[0][0][0][0], 0);
  STAGE(b0, b1, &sm[0][2][0][0], 0);
  STAGE(a0, a1, &sm[0][1][0][0], 32);
  STAGE(b0, b1, &sm[0][3][0][0], 32);

  for (int T = 0; T < NT; ++T) {
    const int buf = T & 1;
    const int nbuf = buf ^ 1;
    const int nko = (T + 1) * 64;        // next tile's K element offset
    const bool st = (T + 1 < NT);

    // phase A (ks=0): consume Ak0,Bk0; stage next tile's Ak0,Bk0
    PHASE(buf, 0,
          { if (st) { STAGE(a0, a1, &sm[nbuf][0][0][0], nko);
                      STAGE(b0, b1, &sm[nbuf][2][0][0], nko); } },
          { asm volatile("s_waitcnt vmcnt(4)" ::: "memory"); });
    // phase B (ks=1): consume Ak1,Bk1; stage next tile's Ak1,Bk1
    PHASE(buf, 1,
          { if (st) { STAGE(a0, a1, &sm[nbuf][1][0][0], nko + 32);
                      STAGE(b0, b1, &sm[nbuf][3][0][0], nko + 32); } },
          { if (T == NT - 1) asm volatile("s_waitcnt vmcnt(0)" ::: "memory");
            else             asm volatile("s_waitcnt vmcnt(4)" ::: "memory"); });
  }

  // Epilogue: C/D layout col=lane&15, row=(lane>>4)*4+reg; fused bias.
  const long cr0 = row0 + wr * 128 + ((lane >> 4) << 2);
  const long cc0 = col0 + wc * 64 + lane15;
#pragma unroll
  for (int j = 0; j < 4; ++j) {
    const long gc = cc0 + j * 16;
    const float bv = bias[gc];
#pragma unroll
    for (int mf = 0; mf < 8; ++mf) {
      float* cp = C + (cr0 + mf * 16) * (long)N + gc;
#pragma unroll
      for (int r = 0; r < 4; ++r)
        cp[(long)r * N] = acc[mf][j][r] + bv;
    }
  }
#undef PHASE
#undef STAGE
}

extern "C" void kernel_launch(void* const* d_in, const int* in_sizes, int n_in,
                              void* d_out, int out_size, void* d_ws, size_t ws_size,
                              hipStream_t stream)
{
  const float* x     = (const float*)d_in[0];
  const int*   wp    = (const int*)d_in[1];
  const float* scale = (const float*)d_in[2];
  const float* zp    = (const float*)d_in[3];
  const float* bias  = (const float*)d_in[4];
  float* out = (float*)d_out;

  bf16* Wb = (bf16*)d_ws;
  bf16* Xb = (bf16*)((char*)d_ws + (size_t)OUT_DIM * IN_DIM * 2);

  dequant_w_kernel<<<(OUT_DIM * (long)IN_DIM / 8) / 256, 256, 0, stream>>>(wp, scale, zp, Wb);
  cvt_x_kernel<<<(M_DIM * (long)IN_DIM / 8) / 256, 256, 0, stream>>>(x, Xb);
  // grid = (8192/256)*(4096/256) = 32*16 = 512 blocks, 512 threads
  gemm_bt_bias_kernel<<<512, 512, 0, stream>>>(Xb, Wb, bias, out);
}